// Round 7
// baseline (213.643 us; speedup 1.0000x reference)
//
#include <hip/hip_runtime.h>
#include <math.h>

#define DPI 3.14159265358979323846
#define RPB 4                                   // rows per persistent block

__device__ __forceinline__ float2 cmul(float2 a, float2 b) {
    return make_float2(a.x*b.x - a.y*b.y, a.x*b.y + a.y*b.x);
}
__device__ __forceinline__ float2 cadd(float2 a, float2 b){ return make_float2(a.x+b.x, a.y+b.y); }
__device__ __forceinline__ float2 csub(float2 a, float2 b){ return make_float2(a.x-b.x, a.y-b.y); }

// W_32^m = (cos, -sin)(2*pi*m/32), m = 0..15
__device__ const float TW32R[16] = {
    1.0f, 0.98078528040323045f, 0.92387953251128676f, 0.83146961230254524f,
    0.70710678118654752f, 0.55557023301960222f, 0.38268343236508977f, 0.19509032201612827f,
    0.0f, -0.19509032201612827f, -0.38268343236508977f, -0.55557023301960222f,
    -0.70710678118654752f, -0.83146961230254524f, -0.92387953251128676f, -0.98078528040323045f };
__device__ const float TW32I[16] = {
    0.0f, -0.19509032201612827f, -0.38268343236508977f, -0.55557023301960222f,
    -0.70710678118654752f, -0.83146961230254524f, -0.92387953251128676f, -0.98078528040323045f,
    -1.0f, -0.98078528040323045f, -0.92387953251128676f, -0.83146961230254524f,
    -0.70710678118654752f, -0.55557023301960222f, -0.38268343236508977f, -0.19509032201612827f };

__device__ const int BR4[16] = {0,8,4,12,2,10,6,14,1,9,5,13,3,11,7,15};

// DIF stage for register FFT of size 16, butterfly half-span H.
template<int H>
__device__ __forceinline__ void stage16(float2* y) {
    #pragma unroll
    for (int g = 0; g < 16; g += 2*H) {
        #pragma unroll
        for (int j = 0; j < H; j++) {
            float2 u = y[g+j], v = y[g+j+H];
            y[g+j] = cadd(u, v);
            float2 d = csub(u, v);
            const int m = j * (16 / H);
            y[g+j+H] = (j == 0) ? d : cmul(d, make_float2(TW32R[m], TW32I[m]));
        }
    }
}
__device__ __forceinline__ void fft16(float2* y) {
    stage16<8>(y); stage16<4>(y); stage16<2>(y); stage16<1>(y);
}   // y[p] = OUT[BR4[p]]

// ws layout (float2):
// [0,8192)       tw1[u*16+k1] = W_8192^{u*k1}   (64 KiB, stage-1 twiddles)
// [8192,8704)    tw2[j*16+k2] = W_512^{j*k2}    (4 KiB, stage-2 twiddles)
// [8704,9728)    twC[t]       = W_2048^t        (unpack base)
// [9728,9736)    twI[i]       = W_16384^i
static __global__ void init_tw(float2* __restrict__ ws) {
    int g = blockIdx.x * 1024 + threadIdx.x;
    if (g < 8192) {
        int uu = g >> 4, k1 = g & 15;
        double th = (double)(uu * k1) * (DPI / 4096.0);
        ws[g] = make_float2((float)cos(th), (float)(-sin(th)));
    } else if (g < 8704) {
        int j = (g - 8192) >> 4, k2 = (g - 8192) & 15;
        double th = (double)(j * k2) * (DPI / 256.0);
        ws[g] = make_float2((float)cos(th), (float)(-sin(th)));
    } else if (g < 9728) {
        int tt = g - 8704;
        double th = (double)tt * (DPI / 1024.0);
        ws[g] = make_float2((float)cos(th), (float)(-sin(th)));
    } else if (g < 9736) {
        int i = g - 9728;
        double th = (double)i * (DPI / 8192.0);
        ws[g] = make_float2((float)cos(th), (float)(-sin(th)));
    }
}

static __global__
__attribute__((amdgpu_flat_work_group_size(1024, 1024)))
__attribute__((amdgpu_waves_per_eu(4, 4)))    // pin to the LDS-capped occupancy -> 128 VGPR budget
void chisq_kernel(const float* __restrict__ tmpl,
                  const float* __restrict__ strn,
                  const float2* __restrict__ ws,
                  float* __restrict__ out,
                  int rows)
{
    __shared__ float2 Z[16384];                 // 128 KiB: [0,8192)=strain, [8192,16384)=template
    float* F = reinterpret_cast<float*>(Z);
    int*   I = reinterpret_cast<int*>(Z);

    const int t    = threadIdx.x;               // 0..1023
    const int half = t >> 9;                    // 0 = strain, 1 = template
    const int u    = t & 511;
    const float ALPHA = 1.1920928955078125e-7f; // 4*DF/fs^2 = 2^-23

    const float2* tw1 = ws;                     // stage-1 twiddle table
    const float2* tw2 = ws + 8192;              // stage-2 twiddle table
    const float2* twC = ws + 8704;
    const float2* twI = ws + 9728;

    float2* Zh = Z + (half << 13);
    const float* sig = half ? tmpl : strn;
    const float2 cv = twC[t];                   // row-invariant unpack twiddle

    const int k1s = u >> 5, js = u & 31;        // row-invariant stage-2 coords
    const int f = u >> 8, k1t = (u >> 4) & 15, k2t = u & 15;   // stage-3 coords

    const int r0 = blockIdx.x * RPB;

    // ---- prologue: load first row's stage-1 inputs into registers ----
    float2 P[16];
    if (r0 < rows) {
        const float2* x = reinterpret_cast<const float2*>(sig + (size_t)r0 * 16384);
        #pragma unroll
        for (int n1 = 0; n1 < 16; n1++) P[n1] = x[n1*512 + u];
    }

    for (int rr = 0; rr < RPB; rr++) {
        const int row = r0 + rr;
        if (row >= rows) break;                  // block-uniform

        // ---- issue twiddle-table loads (L1/L2-hit after first row); fft16(P) covers latency ----
        float2 wp[16];
        #pragma unroll
        for (int k1 = 0; k1 < 16; k1++) wp[k1] = tw1[(u << 4) | k1];
        float2 wq[16];
        #pragma unroll
        for (int k2 = 0; k2 < 16; k2++) wq[k2] = tw2[(js << 4) | k2];

        // -------- stage 1: fft16 over n1 (register data), twiddle W_8192^{u*k1} --------
        fft16(P);                                // pure-register
        __syncthreads();                         // prev iteration's LDS consumers done
        #pragma unroll
        for (int p = 0; p < 16; p++) {
            int k1 = BR4[p];
            float2 val = P[p];
            if (k1 > 0) val = cmul(val, wp[k1]);
            Zh[(u << 4) | (k1 ^ (u & 15))] = val;   // L1[u][k1], swizzled
        }
        __syncthreads();

        float2 y[16];

        // -------- stage 2: fft16 over n2 (u = n2*32 + j), twiddle W_512^{j*k2} --------
        #pragma unroll
        for (int n2 = 0; n2 < 16; n2++)
            y[n2] = Zh[((n2*32 + js) << 4) | (k1s ^ (js & 15))];
        __syncthreads();                          // all L1 reads done before L2 writes
        fft16(y);
        #pragma unroll
        for (int p = 0; p < 16; p++) {
            int k2 = BR4[p];
            float2 val = y[p];
            if (k2 > 0) val = cmul(val, wq[k2]);
            Zh[(k1s << 9) + (k2 << 5) + (js ^ k2)] = val;  // L2[k1][k2][j], swizzled
        }

        // -------- prefetch next row (P dead here; latency hides under stage 3 + reductions) --------
        if (rr + 1 < RPB && row + 1 < rows) {
            const float2* xn = reinterpret_cast<const float2*>(sig + (size_t)(row + 1) * 16384);
            #pragma unroll
            for (int n1 = 0; n1 < 16; n1++) P[n1] = xn[n1*512 + u];
        }
        __syncthreads();

        // -------- stage 3: radix-2 (j2, j2+16) fused into the load + fft16 over j2 --------
        const int base = (k1t << 9) + (k2t << 5);
        if (f == 0) {
            #pragma unroll
            for (int j2 = 0; j2 < 16; j2++) {
                float2 a = Zh[base + (j2 ^ k2t)];
                float2 b = Zh[base + (j2 ^ k2t) + 16];
                y[j2] = cadd(a, b);
            }
        } else {
            #pragma unroll
            for (int j2 = 0; j2 < 16; j2++) {
                float2 a = Zh[base + (j2 ^ k2t)];
                float2 b = Zh[base + (j2 ^ k2t) + 16];
                y[j2] = cmul(csub(a, b), make_float2(TW32R[j2], TW32I[j2]));
            }
        }
        __syncthreads();                          // all L2 reads done before spectrum store
        fft16(y);
        #pragma unroll
        for (int p = 0; p < 16; p++) {
            int s2 = BR4[p];
            int k = k1t + (k2t << 4) + (f << 8) + (s2 << 9);
            Zh[(k & ~31) | ((k & 31) ^ ((k >> 5) & 31))] = y[p];  // natural k, swizzled low5
        }
        __syncthreads();                          // both spectra ready

        // -------- rfft unpack of both spectra + pointwise products, 8 bins/thread --------
        float2* ZS = Z;
        float2* ZH = Z + 8192;
        float2 zs0 = ZS[0], zh0 = ZH[0];
        const float s_nyq = zs0.x - zs0.y;
        const float h_nyq = zh0.x - zh0.y;

        float hh[8], hs[8];                       // |H|^2, Re(conj(H)*S)
        #pragma unroll
        for (int i = 0; i < 8; i++) {
            int k = (t << 3) + i;
            int m = (8192 - k) & 8191;
            int ak = (k & ~31) | ((k & 31) ^ ((k >> 5) & 31));
            int am = (m & ~31) | ((m & 31) ^ ((m >> 5) & 31));
            float2 As = ZS[ak], Bs = ZS[am];
            float2 Ah = ZH[ak], Bh = ZH[am];
            float2 w = cmul(cv, twI[i]);          // W_16384^k
            float Er = 0.5f*(As.x + Bs.x), Ei = 0.5f*(As.y - Bs.y);
            float Dr = 0.5f*(As.x - Bs.x), Di = 0.5f*(As.y + Bs.y);
            float sr = Er + w.x*Di + w.y*Dr;
            float si = Ei + w.y*Di - w.x*Dr;
            Er = 0.5f*(Ah.x + Bh.x); Ei = 0.5f*(Ah.y - Bh.y);
            Dr = 0.5f*(Ah.x - Bh.x); Di = 0.5f*(Ah.y + Bh.y);
            float hr = Er + w.x*Di + w.y*Dr;
            float hi = Ei + w.y*Di - w.x*Dr;
            hh[i] = hr*hr + hi*hi;
            hs[i] = hr*sr + hi*si;
        }
        __syncthreads();                          // all spectrum reads done; LDS free

        // -------- cum_h: wave shuffle scan over 16 waves --------
        const int SCANW = 16500;                  // 16 floats (upper half dead)
        const int EDG   = 16520;                  // 17 ints
        const int BINS  = 16544;                  // 16 floats
        const int TOT   = 16561;

        float run = 0.f;
        #pragma unroll
        for (int i = 0; i < 8; i++) run += ALPHA * hh[i];

        const int lane = t & 63, wid = t >> 6;
        float v = run;
        #pragma unroll
        for (int off = 1; off < 64; off <<= 1) {
            float o = __shfl_up(v, off, 64);
            if (lane >= off) v += o;
        }
        if (lane == 63) F[SCANW + wid] = v;
        __syncthreads();
        float wbase = 0.f;
        #pragma unroll
        for (int w2 = 0; w2 < 15; w2++) if (w2 < wid) wbase += F[SCANW + w2];
        float base2 = wbase + v - run;            // exclusive prefix

        float cum = base2;
        #pragma unroll
        for (int i = 0; i < 8; i++) {             // cum at phys(k)=k+(k>>5)
            cum += ALPHA * hh[i];
            int k = (t << 3) + i;
            F[k + (k >> 5)] = cum;
        }
        if (t == 1023) F[8448] = cum + ALPHA * h_nyq * h_nyq;   // cum_h[8192]
        __syncthreads();

        // -------- edges (searchsorted right) + bin init --------
        float total_h = F[8448];
        if (t < 17) {
            float target = (float)t * 0.0625f * total_h;
            int lo = 0, hi = 8193;
            while (lo < hi) {
                int mid = (lo + hi) >> 1;
                float vv = F[mid + (mid >> 5)];
                if (vv <= target) lo = mid + 1; else hi = mid;
            }
            I[EDG + t] = lo < 8192 ? lo : 8192;
        }
        if (t >= 64 && t < 80) F[BINS + (t - 64)] = 0.f;
        if (t == 80) F[TOT] = 0.f;
        __syncthreads();

        int e[17];
        #pragma unroll
        for (int i = 0; i < 17; i++) e[i] = I[EDG + i];

        float invs = 1.0f / sqrtf(total_h);
        float qs   = ALPHA * invs;

        // -------- segmented bin sums + total --------
        float tot = 0.f, acc = 0.f;
        int   cur = -1;
        #pragma unroll
        for (int i = 0; i < 8; i++) {
            int   k = (t << 3) + i;
            float r = qs * hs[i];
            tot += r;
            int bn = -1;                          // k in bin bn iff e[bn] < k <= e[bn+1]
            #pragma unroll
            for (int j = 0; j < 17; j++) bn += (e[j] < k) ? 1 : 0;
            if (bn != cur) {
                if (cur >= 0) atomicAdd(&F[BINS + cur], acc);
                acc = 0.f;
                cur = bn;
            }
            acc += r;
        }
        if (cur >= 0) atomicAdd(&F[BINS + cur], acc);

        #pragma unroll
        for (int off = 32; off > 0; off >>= 1) tot += __shfl_down(tot, off);
        if ((t & 63) == 0) atomicAdd(&F[TOT], tot);

        if (t == 0) {                             // Nyquist term (k = 8192)
            float rn = qs * (h_nyq * s_nyq);
            atomicAdd(&F[TOT], rn);
            int bn = -1;
            #pragma unroll
            for (int j = 0; j < 17; j++) bn += (e[j] < 8192) ? 1 : 0;
            if (bn >= 0) atomicAdd(&F[BINS + bn], rn);
        }
        __syncthreads();

        if (t == 0) {
            float total = F[TOT];
            float mean  = total * 0.0625f;
            float chisq = 0.f;
            #pragma unroll
            for (int j = 0; j < 16; j++) {
                float d = F[BINS + j] - mean;
                chisq += d * d;
            }
            out[row] = chisq * (16.0f / 15.0f);
        }
        // loop-top __syncthreads() protects BINS/TOT reads vs next stage-1 stores
    }
}

extern "C" void kernel_launch(void* const* d_in, const int* in_sizes, int n_in,
                              void* d_out, int out_size, void* d_ws, size_t ws_size,
                              hipStream_t stream) {
    const float* tmpl = (const float*)d_in[0];
    const float* strn = (const float*)d_in[1];
    float* outp = (float*)d_out;
    float2* ws  = (float2*)d_ws;                 // ~78 KiB twiddle tables

    int rows = in_sizes[0] / 16384;              // 1024
    int nblk = (rows + RPB - 1) / RPB;           // 256 persistent blocks (1 per CU)

    hipLaunchKernelGGL(init_tw, dim3(10), dim3(1024), 0, stream, ws);
    hipLaunchKernelGGL(chisq_kernel, dim3(nblk), dim3(1024), 0, stream,
                       tmpl, strn, ws, outp, rows);
}

// Round 8
// 169.450 us; speedup vs baseline: 1.2608x; 1.2608x over previous
//
#include <hip/hip_runtime.h>
#include <math.h>

#define DPI 3.14159265358979323846
#define RPB 4                                   // rows per persistent block

__device__ __forceinline__ float2 cmul(float2 a, float2 b) {
    return make_float2(a.x*b.x - a.y*b.y, a.x*b.y + a.y*b.x);
}
__device__ __forceinline__ float2 cadd(float2 a, float2 b){ return make_float2(a.x+b.x, a.y+b.y); }
__device__ __forceinline__ float2 csub(float2 a, float2 b){ return make_float2(a.x-b.x, a.y-b.y); }

// W_32^m = (cos, -sin)(2*pi*m/32), m = 0..15
__device__ const float TW32R[16] = {
    1.0f, 0.98078528040323045f, 0.92387953251128676f, 0.83146961230254524f,
    0.70710678118654752f, 0.55557023301960222f, 0.38268343236508977f, 0.19509032201612827f,
    0.0f, -0.19509032201612827f, -0.38268343236508977f, -0.55557023301960222f,
    -0.70710678118654752f, -0.83146961230254524f, -0.92387953251128676f, -0.98078528040323045f };
__device__ const float TW32I[16] = {
    0.0f, -0.19509032201612827f, -0.38268343236508977f, -0.55557023301960222f,
    -0.70710678118654752f, -0.83146961230254524f, -0.92387953251128676f, -0.98078528040323045f,
    -1.0f, -0.98078528040323045f, -0.92387953251128676f, -0.83146961230254524f,
    -0.70710678118654752f, -0.55557023301960222f, -0.38268343236508977f, -0.19509032201612827f };

__device__ const int BR4[16] = {0,8,4,12,2,10,6,14,1,9,5,13,3,11,7,15};

// DIF stage for register FFT of size 16, butterfly half-span H.
template<int H>
__device__ __forceinline__ void stage16(float2* y) {
    #pragma unroll
    for (int g = 0; g < 16; g += 2*H) {
        #pragma unroll
        for (int j = 0; j < H; j++) {
            float2 u = y[g+j], v = y[g+j+H];
            y[g+j] = cadd(u, v);
            float2 d = csub(u, v);
            const int m = j * (16 / H);
            y[g+j+H] = (j == 0) ? d : cmul(d, make_float2(TW32R[m], TW32I[m]));
        }
    }
}
__device__ __forceinline__ void fft16(float2* y) {
    stage16<8>(y); stage16<4>(y); stage16<2>(y); stage16<1>(y);
}   // y[p] = OUT[BR4[p]]

// ws layout (float2):
// [0,8192)       tw1[u*16+k1] = W_8192^{u*k1}   (64 KiB, stage-1 twiddles)
// [8192,8704)    tw2[j*16+k2] = W_512^{j*k2}    (4 KiB, stage-2 twiddles)
// [8704,16896)   twU[k]       = W_16384^k       (64 KiB, unpack twiddles)
static __global__ void init_tw(float2* __restrict__ ws) {
    int g = blockIdx.x * 1024 + threadIdx.x;
    if (g < 8192) {
        int uu = g >> 4, k1 = g & 15;
        double th = (double)(uu * k1) * (DPI / 4096.0);
        ws[g] = make_float2((float)cos(th), (float)(-sin(th)));
    } else if (g < 8704) {
        int j = (g - 8192) >> 4, k2 = (g - 8192) & 15;
        double th = (double)(j * k2) * (DPI / 256.0);
        ws[g] = make_float2((float)cos(th), (float)(-sin(th)));
    } else if (g < 16896) {
        int k = g - 8704;
        double th = (double)k * (DPI / 8192.0);
        ws[g] = make_float2((float)cos(th), (float)(-sin(th)));
    }
}

__launch_bounds__(1024, 4)
static __global__ void chisq_kernel(const float* __restrict__ tmpl,
                                    const float* __restrict__ strn,
                                    const float2* __restrict__ ws,
                                    float* __restrict__ out,
                                    int rows)
{
    __shared__ float2 Z[16384];                 // 128 KiB: [0,8192)=strain, [8192,16384)=template
    float* F = reinterpret_cast<float*>(Z);
    int*   I = reinterpret_cast<int*>(Z);

    const int t    = threadIdx.x;               // 0..1023
    const int half = t >> 9;                    // 0 = strain, 1 = template
    const int u    = t & 511;
    const float ALPHA = 1.1920928955078125e-7f; // 4*DF/fs^2 = 2^-23

    const float2* tw1 = ws;                     // stage-1 twiddles
    const float2* tw2 = ws + 8192;              // stage-2 twiddles
    const float2* twU = ws + 8704;              // unpack twiddles

    float2* Zh = Z + (half << 13);
    const float* sig = half ? tmpl : strn;

    const int k1s = u >> 5, js = u & 31;        // stage-2 coords
    const int f = u >> 8, k1t = (u >> 4) & 15, k2t = u & 15;   // stage-3 coords

    const int r0 = blockIdx.x * RPB;

    for (int rr = 0; rr < RPB; rr++) {
        const int row = r0 + rr;
        if (row >= rows) break;                  // block-uniform

        float2 y[16];

        // -------- load row + stage 1: fft16 over n1, twiddle W_8192^{u*k1} --------
        {
            const float2* x = reinterpret_cast<const float2*>(sig + (size_t)row * 16384);
            #pragma unroll
            for (int n1 = 0; n1 < 16; n1++) y[n1] = x[n1*512 + u];
        }
        fft16(y);                                // pure-register; overlaps load drain
        __syncthreads();                         // prev iteration's LDS consumers done
        #pragma unroll
        for (int p = 0; p < 16; p++) {
            int k1 = BR4[p];
            float2 val = y[p];
            if (k1 > 0) val = cmul(val, tw1[(u << 4) | k1]);   // short-lived table load
            Zh[(u << 4) | (k1 ^ (u & 15))] = val;   // L1[u][k1], swizzled
        }
        __syncthreads();

        // -------- stage 2: fft16 over n2 (u = n2*32 + j), twiddle W_512^{j*k2} --------
        #pragma unroll
        for (int n2 = 0; n2 < 16; n2++)
            y[n2] = Zh[((n2*32 + js) << 4) | (k1s ^ (js & 15))];
        __syncthreads();                          // all L1 reads done before L2 writes
        fft16(y);
        #pragma unroll
        for (int p = 0; p < 16; p++) {
            int k2 = BR4[p];
            float2 val = y[p];
            if (k2 > 0) val = cmul(val, tw2[(js << 4) | k2]);  // short-lived table load
            Zh[(k1s << 9) + (k2 << 5) + (js ^ k2)] = val;      // L2[k1][k2][j], swizzled
        }
        __syncthreads();

        // -------- stage 3: radix-2 (j2, j2+16) fused into the load + fft16 over j2 --------
        const int base = (k1t << 9) + (k2t << 5);
        if (f == 0) {
            #pragma unroll
            for (int j2 = 0; j2 < 16; j2++) {
                float2 a = Zh[base + (j2 ^ k2t)];
                float2 b = Zh[base + (j2 ^ k2t) + 16];
                y[j2] = cadd(a, b);
            }
        } else {
            #pragma unroll
            for (int j2 = 0; j2 < 16; j2++) {
                float2 a = Zh[base + (j2 ^ k2t)];
                float2 b = Zh[base + (j2 ^ k2t) + 16];
                y[j2] = cmul(csub(a, b), make_float2(TW32R[j2], TW32I[j2]));
            }
        }
        __syncthreads();                          // all L2 reads done before spectrum store
        fft16(y);
        #pragma unroll
        for (int p = 0; p < 16; p++) {
            int s2 = BR4[p];
            int k = k1t + (k2t << 4) + (f << 8) + (s2 << 9);
            Zh[(k & ~31) | ((k & 31) ^ ((k >> 5) & 31))] = y[p];  // natural k, swizzled low5
        }
        __syncthreads();                          // both spectra ready

        // -------- rfft unpack of both spectra + pointwise products, 8 bins/thread --------
        float2* ZS = Z;
        float2* ZH = Z + 8192;
        float2 zs0 = ZS[0], zh0 = ZH[0];
        const float s_nyq = zs0.x - zs0.y;
        const float h_nyq = zh0.x - zh0.y;

        float hh[8], hs[8];                       // |H|^2, Re(conj(H)*S)
        #pragma unroll
        for (int i = 0; i < 8; i++) {
            int k = (t << 3) + i;
            int m = (8192 - k) & 8191;
            int ak = (k & ~31) | ((k & 31) ^ ((k >> 5) & 31));
            int am = (m & ~31) | ((m & 31) ^ ((m >> 5) & 31));
            float2 As = ZS[ak], Bs = ZS[am];
            float2 Ah = ZH[ak], Bh = ZH[am];
            float2 w = twU[k];                    // W_16384^k, coalesced table load
            float Er = 0.5f*(As.x + Bs.x), Ei = 0.5f*(As.y - Bs.y);
            float Dr = 0.5f*(As.x - Bs.x), Di = 0.5f*(As.y + Bs.y);
            float sr = Er + w.x*Di + w.y*Dr;
            float si = Ei + w.y*Di - w.x*Dr;
            Er = 0.5f*(Ah.x + Bh.x); Ei = 0.5f*(Ah.y - Bh.y);
            Dr = 0.5f*(Ah.x - Bh.x); Di = 0.5f*(Ah.y + Bh.y);
            float hr = Er + w.x*Di + w.y*Dr;
            float hi = Ei + w.y*Di - w.x*Dr;
            hh[i] = hr*hr + hi*hi;
            hs[i] = hr*sr + hi*si;
        }
        __syncthreads();                          // all spectrum reads done; LDS free

        // -------- cum_h: wave shuffle scan over 16 waves --------
        const int SCANW = 16500;                  // 16 floats (upper half dead)
        const int EDG   = 16520;                  // 17 ints
        const int BINS  = 16544;                  // 16 floats
        const int TOT   = 16561;

        float run = 0.f;
        #pragma unroll
        for (int i = 0; i < 8; i++) run += ALPHA * hh[i];

        const int lane = t & 63, wid = t >> 6;
        float v = run;
        #pragma unroll
        for (int off = 1; off < 64; off <<= 1) {
            float o = __shfl_up(v, off, 64);
            if (lane >= off) v += o;
        }
        if (lane == 63) F[SCANW + wid] = v;
        __syncthreads();
        float wbase = 0.f;
        #pragma unroll
        for (int w2 = 0; w2 < 15; w2++) if (w2 < wid) wbase += F[SCANW + w2];
        float base2 = wbase + v - run;            // exclusive prefix

        float cum = base2;
        #pragma unroll
        for (int i = 0; i < 8; i++) {             // cum at phys(k)=k+(k>>5)
            cum += ALPHA * hh[i];
            int k = (t << 3) + i;
            F[k + (k >> 5)] = cum;
        }
        if (t == 1023) F[8448] = cum + ALPHA * h_nyq * h_nyq;   // cum_h[8192]
        __syncthreads();

        // -------- edges (searchsorted right) + bin init --------
        float total_h = F[8448];
        if (t < 17) {
            float target = (float)t * 0.0625f * total_h;
            int lo = 0, hi = 8193;
            while (lo < hi) {
                int mid = (lo + hi) >> 1;
                float vv = F[mid + (mid >> 5)];
                if (vv <= target) lo = mid + 1; else hi = mid;
            }
            I[EDG + t] = lo < 8192 ? lo : 8192;
        }
        if (t >= 64 && t < 80) F[BINS + (t - 64)] = 0.f;
        if (t == 80) F[TOT] = 0.f;
        __syncthreads();

        int e[17];
        #pragma unroll
        for (int i = 0; i < 17; i++) e[i] = I[EDG + i];

        float invs = 1.0f / sqrtf(total_h);
        float qs   = ALPHA * invs;

        // -------- segmented bin sums + total --------
        float tot = 0.f, acc = 0.f;
        int   cur = -1;
        #pragma unroll
        for (int i = 0; i < 8; i++) {
            int   k = (t << 3) + i;
            float r = qs * hs[i];
            tot += r;
            int bn = -1;                          // k in bin bn iff e[bn] < k <= e[bn+1]
            #pragma unroll
            for (int j = 0; j < 17; j++) bn += (e[j] < k) ? 1 : 0;
            if (bn != cur) {
                if (cur >= 0) atomicAdd(&F[BINS + cur], acc);
                acc = 0.f;
                cur = bn;
            }
            acc += r;
        }
        if (cur >= 0) atomicAdd(&F[BINS + cur], acc);

        #pragma unroll
        for (int off = 32; off > 0; off >>= 1) tot += __shfl_down(tot, off);
        if ((t & 63) == 0) atomicAdd(&F[TOT], tot);

        if (t == 0) {                             // Nyquist term (k = 8192)
            float rn = qs * (h_nyq * s_nyq);
            atomicAdd(&F[TOT], rn);
            int bn = -1;
            #pragma unroll
            for (int j = 0; j < 17; j++) bn += (e[j] < 8192) ? 1 : 0;
            if (bn >= 0) atomicAdd(&F[BINS + bn], rn);
        }
        __syncthreads();

        if (t == 0) {
            float total = F[TOT];
            float mean  = total * 0.0625f;
            float chisq = 0.f;
            #pragma unroll
            for (int j = 0; j < 16; j++) {
                float d = F[BINS + j] - mean;
                chisq += d * d;
            }
            out[row] = chisq * (16.0f / 15.0f);
        }
        // next iteration's pre-store __syncthreads() protects BINS/TOT reads
    }
}

extern "C" void kernel_launch(void* const* d_in, const int* in_sizes, int n_in,
                              void* d_out, int out_size, void* d_ws, size_t ws_size,
                              hipStream_t stream) {
    const float* tmpl = (const float*)d_in[0];
    const float* strn = (const float*)d_in[1];
    float* outp = (float*)d_out;
    float2* ws  = (float2*)d_ws;                 // ~132 KiB twiddle tables

    int rows = in_sizes[0] / 16384;              // 1024
    int nblk = (rows + RPB - 1) / RPB;           // 256 persistent blocks (1 per CU)

    hipLaunchKernelGGL(init_tw, dim3(17), dim3(1024), 0, stream, ws);
    hipLaunchKernelGGL(chisq_kernel, dim3(nblk), dim3(1024), 0, stream,
                       tmpl, strn, ws, outp, rows);
}

// Round 9
// 149.293 us; speedup vs baseline: 1.4310x; 1.1350x over previous
//
#include <hip/hip_runtime.h>
#include <math.h>

#define DPI 3.14159265358979323846
#define RPB 4                                   // rows per persistent block

__device__ __forceinline__ float2 cmul(float2 a, float2 b) {
    return make_float2(a.x*b.x - a.y*b.y, a.x*b.y + a.y*b.x);
}
__device__ __forceinline__ float2 cadd(float2 a, float2 b){ return make_float2(a.x+b.x, a.y+b.y); }
__device__ __forceinline__ float2 csub(float2 a, float2 b){ return make_float2(a.x-b.x, a.y-b.y); }

// W_32^m = (cos, -sin)(2*pi*m/32), m = 0..15
__device__ const float TW32R[16] = {
    1.0f, 0.98078528040323045f, 0.92387953251128676f, 0.83146961230254524f,
    0.70710678118654752f, 0.55557023301960222f, 0.38268343236508977f, 0.19509032201612827f,
    0.0f, -0.19509032201612827f, -0.38268343236508977f, -0.55557023301960222f,
    -0.70710678118654752f, -0.83146961230254524f, -0.92387953251128676f, -0.98078528040323045f };
__device__ const float TW32I[16] = {
    0.0f, -0.19509032201612827f, -0.38268343236508977f, -0.55557023301960222f,
    -0.70710678118654752f, -0.83146961230254524f, -0.92387953251128676f, -0.98078528040323045f,
    -1.0f, -0.98078528040323045f, -0.92387953251128676f, -0.83146961230254524f,
    -0.70710678118654752f, -0.55557023301960222f, -0.38268343236508977f, -0.19509032201612827f };

__device__ const int BR4[16] = {0,8,4,12,2,10,6,14,1,9,5,13,3,11,7,15};

// DIF stage for register FFT of size 16, butterfly half-span H.
template<int H>
__device__ __forceinline__ void stage16(float2* y) {
    #pragma unroll
    for (int g = 0; g < 16; g += 2*H) {
        #pragma unroll
        for (int j = 0; j < H; j++) {
            float2 u = y[g+j], v = y[g+j+H];
            y[g+j] = cadd(u, v);
            float2 d = csub(u, v);
            const int m = j * (16 / H);
            y[g+j+H] = (j == 0) ? d : cmul(d, make_float2(TW32R[m], TW32I[m]));
        }
    }
}
__device__ __forceinline__ void fft16(float2* y) {
    stage16<8>(y); stage16<4>(y); stage16<2>(y); stage16<1>(y);
}   // y[p] = OUT[BR4[p]]

// wp[m] = w^m, m=0..15, mult depth <= 3 (VALU-computed: no load-batching register pressure)
__device__ __forceinline__ void pow16(float2 w, float2* wp) {
    wp[0] = make_float2(1.f, 0.f);
    wp[1] = w;
    wp[2] = cmul(w, w);
    wp[3] = cmul(wp[2], w);
    wp[4] = cmul(wp[2], wp[2]);
    wp[5] = cmul(wp[4], wp[1]);
    wp[6] = cmul(wp[4], wp[2]);
    wp[7] = cmul(wp[4], wp[3]);
    wp[8] = cmul(wp[4], wp[4]);
    wp[9] = cmul(wp[8], wp[1]);
    wp[10] = cmul(wp[8], wp[2]);
    wp[11] = cmul(wp[8], wp[3]);
    wp[12] = cmul(wp[8], wp[4]);
    wp[13] = cmul(wp[8], wp[5]);
    wp[14] = cmul(wp[8], wp[6]);
    wp[15] = cmul(wp[8], wp[7]);
}

// ws layout (float2): [0,512) W_8192^u | [512,544) W_512^j | [544,1568) W_2048^t | [1568,1576) W_16384^i
static __global__ void init_tw(float2* __restrict__ ws) {
    int g = blockIdx.x * 1024 + threadIdx.x;
    if (g < 512) {
        ws[g] = make_float2((float)cos(DPI*g/4096.0), (float)(-sin(DPI*g/4096.0)));
    } else if (g < 544) {
        int j = g - 512;
        ws[g] = make_float2((float)cos(DPI*j/256.0), (float)(-sin(DPI*j/256.0)));
    } else if (g < 1568) {
        int q = g - 544;
        ws[g] = make_float2((float)cos(DPI*q/1024.0), (float)(-sin(DPI*q/1024.0)));
    } else if (g < 1576) {
        int i = g - 1568;
        ws[g] = make_float2((float)cos(DPI*i/8192.0), (float)(-sin(DPI*i/8192.0)));
    }
}

__launch_bounds__(1024, 4)
static __global__ void chisq_kernel(const float* __restrict__ tmpl,
                                    const float* __restrict__ strn,
                                    const float2* __restrict__ ws,
                                    float* __restrict__ out,
                                    int rows)
{
    __shared__ float2 Z[16384];                 // 128 KiB: [0,8192)=strain, [8192,16384)=template
    float* F = reinterpret_cast<float*>(Z);
    int*   I = reinterpret_cast<int*>(Z);

    const int t    = threadIdx.x;               // 0..1023
    const int half = t >> 9;                    // 0 = strain, 1 = template
    const int u    = t & 511;
    const float ALPHA = 1.1920928955078125e-7f; // 4*DF/fs^2 = 2^-23

    const float2* tw8192 = ws;                  // W_8192^u, u<512
    const float2* tw512  = ws + 512;            // W_512^j,  j<32
    const float2* twC    = ws + 544;            // W_2048^t, t<1024
    const float2* twI    = ws + 1568;           // W_16384^i, i<8

    float2* Zh = Z + (half << 13);
    const float* sig = half ? tmpl : strn;
    const float2 cv = twC[t];                   // row-invariant unpack twiddle

    const int k1s = u >> 5, js = u & 31;        // stage-2 coords
    const int f = u >> 8, k1t = (u >> 4) & 15, k2t = u & 15;   // stage-3 coords

    const int r0 = blockIdx.x * RPB;

    // Keep the row loop a REAL loop: each iteration must stay its own scheduling
    // region, or the scheduler hoists next-row loads and spills at the 64-VGPR cap.
    #pragma clang loop unroll(disable)
    for (int rr = 0; rr < RPB; rr++) {
        const int row = r0 + rr;
        if (row >= rows) break;                  // block-uniform

        float2 y[16];

        // -------- load row + stage 1: fft16 over n1, twiddle W_8192^{u*k1} --------
        {
            const float2* x = reinterpret_cast<const float2*>(sig + (size_t)row * 16384);
            #pragma unroll
            for (int n1 = 0; n1 < 16; n1++) y[n1] = x[n1*512 + u];
        }
        fft16(y);                                // pure-register; overlaps load drain
        __syncthreads();                         // prev iteration's LDS consumers done
        {
            float2 wp[16]; pow16(tw8192[u], wp);
            #pragma unroll
            for (int p = 0; p < 16; p++) {
                int k1 = BR4[p];
                float2 val = y[p];
                if (k1 > 0) val = cmul(val, wp[k1]);
                Zh[(u << 4) | (k1 ^ (u & 15))] = val;   // L1[u][k1], swizzled
            }
        }
        __syncthreads();

        // -------- stage 2: fft16 over n2 (u = n2*32 + j), twiddle W_512^{j*k2} --------
        #pragma unroll
        for (int n2 = 0; n2 < 16; n2++)
            y[n2] = Zh[((n2*32 + js) << 4) | (k1s ^ (js & 15))];
        __syncthreads();                          // all L1 reads done before L2 writes
        fft16(y);
        {
            float2 wq[16]; pow16(tw512[js], wq);
            #pragma unroll
            for (int p = 0; p < 16; p++) {
                int k2 = BR4[p];
                float2 val = y[p];
                if (k2 > 0) val = cmul(val, wq[k2]);
                Zh[(k1s << 9) + (k2 << 5) + (js ^ k2)] = val;  // L2[k1][k2][j], swizzled
            }
        }
        __syncthreads();

        // -------- stage 3: radix-2 (j2, j2+16) fused into the load + fft16 over j2 --------
        const int base = (k1t << 9) + (k2t << 5);
        if (f == 0) {
            #pragma unroll
            for (int j2 = 0; j2 < 16; j2++) {
                float2 a = Zh[base + (j2 ^ k2t)];
                float2 b = Zh[base + (j2 ^ k2t) + 16];
                y[j2] = cadd(a, b);
            }
        } else {
            #pragma unroll
            for (int j2 = 0; j2 < 16; j2++) {
                float2 a = Zh[base + (j2 ^ k2t)];
                float2 b = Zh[base + (j2 ^ k2t) + 16];
                y[j2] = cmul(csub(a, b), make_float2(TW32R[j2], TW32I[j2]));
            }
        }
        __syncthreads();                          // all L2 reads done before spectrum store
        fft16(y);
        #pragma unroll
        for (int p = 0; p < 16; p++) {
            int s2 = BR4[p];
            int k = k1t + (k2t << 4) + (f << 8) + (s2 << 9);
            Zh[(k & ~31) | ((k & 31) ^ ((k >> 5) & 31))] = y[p];  // natural k, swizzled low5
        }
        __syncthreads();                          // both spectra ready

        // -------- rfft unpack of both spectra + pointwise products, 8 bins/thread --------
        float2* ZS = Z;
        float2* ZH = Z + 8192;
        float2 zs0 = ZS[0], zh0 = ZH[0];
        const float s_nyq = zs0.x - zs0.y;
        const float h_nyq = zh0.x - zh0.y;

        float hh[8], hs[8];                       // |H|^2, Re(conj(H)*S)
        #pragma unroll
        for (int i = 0; i < 8; i++) {
            int k = (t << 3) + i;
            int m = (8192 - k) & 8191;
            int ak = (k & ~31) | ((k & 31) ^ ((k >> 5) & 31));
            int am = (m & ~31) | ((m & 31) ^ ((m >> 5) & 31));
            float2 As = ZS[ak], Bs = ZS[am];
            float2 Ah = ZH[ak], Bh = ZH[am];
            float2 w = cmul(cv, twI[i]);          // W_16384^k
            float Er = 0.5f*(As.x + Bs.x), Ei = 0.5f*(As.y - Bs.y);
            float Dr = 0.5f*(As.x - Bs.x), Di = 0.5f*(As.y + Bs.y);
            float sr = Er + w.x*Di + w.y*Dr;
            float si = Ei + w.y*Di - w.x*Dr;
            Er = 0.5f*(Ah.x + Bh.x); Ei = 0.5f*(Ah.y - Bh.y);
            Dr = 0.5f*(Ah.x - Bh.x); Di = 0.5f*(Ah.y + Bh.y);
            float hr = Er + w.x*Di + w.y*Dr;
            float hi = Ei + w.y*Di - w.x*Dr;
            hh[i] = hr*hr + hi*hi;
            hs[i] = hr*sr + hi*si;
        }
        __syncthreads();                          // all spectrum reads done; LDS free

        // -------- cum_h: wave shuffle scan over 16 waves --------
        const int SCANW = 16500;                  // 16 floats (upper half dead)
        const int EDG   = 16520;                  // 17 ints
        const int BINS  = 16544;                  // 16 floats
        const int TOT   = 16561;

        float run = 0.f;
        #pragma unroll
        for (int i = 0; i < 8; i++) run += ALPHA * hh[i];

        const int lane = t & 63, wid = t >> 6;
        float v = run;
        #pragma unroll
        for (int off = 1; off < 64; off <<= 1) {
            float o = __shfl_up(v, off, 64);
            if (lane >= off) v += o;
        }
        if (lane == 63) F[SCANW + wid] = v;
        __syncthreads();
        float wbase = 0.f;
        #pragma unroll
        for (int w2 = 0; w2 < 15; w2++) if (w2 < wid) wbase += F[SCANW + w2];
        float base2 = wbase + v - run;            // exclusive prefix

        float cum = base2;
        #pragma unroll
        for (int i = 0; i < 8; i++) {             // cum at phys(k)=k+(k>>5)
            cum += ALPHA * hh[i];
            int k = (t << 3) + i;
            F[k + (k >> 5)] = cum;
        }
        if (t == 1023) F[8448] = cum + ALPHA * h_nyq * h_nyq;   // cum_h[8192]
        __syncthreads();

        // -------- edges (searchsorted right) + bin init --------
        float total_h = F[8448];
        if (t < 17) {
            float target = (float)t * 0.0625f * total_h;
            int lo = 0, hi = 8193;
            while (lo < hi) {
                int mid = (lo + hi) >> 1;
                float vv = F[mid + (mid >> 5)];
                if (vv <= target) lo = mid + 1; else hi = mid;
            }
            I[EDG + t] = lo < 8192 ? lo : 8192;
        }
        if (t >= 64 && t < 80) F[BINS + (t - 64)] = 0.f;
        if (t == 80) F[TOT] = 0.f;
        __syncthreads();

        int e[17];
        #pragma unroll
        for (int i = 0; i < 17; i++) e[i] = I[EDG + i];

        float invs = 1.0f / sqrtf(total_h);
        float qs   = ALPHA * invs;

        // -------- segmented bin sums + total --------
        float tot = 0.f, acc = 0.f;
        int   cur = -1;
        #pragma unroll
        for (int i = 0; i < 8; i++) {
            int   k = (t << 3) + i;
            float r = qs * hs[i];
            tot += r;
            int bn = -1;                          // k in bin bn iff e[bn] < k <= e[bn+1]
            #pragma unroll
            for (int j = 0; j < 17; j++) bn += (e[j] < k) ? 1 : 0;
            if (bn != cur) {
                if (cur >= 0) atomicAdd(&F[BINS + cur], acc);
                acc = 0.f;
                cur = bn;
            }
            acc += r;
        }
        if (cur >= 0) atomicAdd(&F[BINS + cur], acc);

        #pragma unroll
        for (int off = 32; off > 0; off >>= 1) tot += __shfl_down(tot, off);
        if ((t & 63) == 0) atomicAdd(&F[TOT], tot);

        if (t == 0) {                             // Nyquist term (k = 8192)
            float rn = qs * (h_nyq * s_nyq);
            atomicAdd(&F[TOT], rn);
            int bn = -1;
            #pragma unroll
            for (int j = 0; j < 17; j++) bn += (e[j] < 8192) ? 1 : 0;
            if (bn >= 0) atomicAdd(&F[BINS + bn], rn);
        }
        __syncthreads();

        if (t == 0) {
            float total = F[TOT];
            float mean  = total * 0.0625f;
            float chisq = 0.f;
            #pragma unroll
            for (int j = 0; j < 16; j++) {
                float d = F[BINS + j] - mean;
                chisq += d * d;
            }
            out[row] = chisq * (16.0f / 15.0f);
        }
        // next iteration's post-fft16 __syncthreads() protects BINS/TOT reads
    }
}

extern "C" void kernel_launch(void* const* d_in, const int* in_sizes, int n_in,
                              void* d_out, int out_size, void* d_ws, size_t ws_size,
                              hipStream_t stream) {
    const float* tmpl = (const float*)d_in[0];
    const float* strn = (const float*)d_in[1];
    float* outp = (float*)d_out;
    float2* ws  = (float2*)d_ws;                 // ~12.3 KiB twiddle tables

    int rows = in_sizes[0] / 16384;              // 1024
    int nblk = (rows + RPB - 1) / RPB;           // 256 persistent blocks (1 per CU)

    hipLaunchKernelGGL(init_tw, dim3(2), dim3(1024), 0, stream, ws);
    hipLaunchKernelGGL(chisq_kernel, dim3(nblk), dim3(1024), 0, stream,
                       tmpl, strn, ws, outp, rows);
}

// Round 10
// 114.653 us; speedup vs baseline: 1.8634x; 1.3021x over previous
//
#include <hip/hip_runtime.h>
#include <math.h>

#define DPI 3.14159265358979323846
#define RPB 4                                   // rows per persistent block

__device__ __forceinline__ float2 cmul(float2 a, float2 b) {
    return make_float2(a.x*b.x - a.y*b.y, a.x*b.y + a.y*b.x);
}
__device__ __forceinline__ float2 cadd(float2 a, float2 b){ return make_float2(a.x+b.x, a.y+b.y); }
__device__ __forceinline__ float2 csub(float2 a, float2 b){ return make_float2(a.x-b.x, a.y-b.y); }

// W_32^m = (cos, -sin)(2*pi*m/32), m = 0..15
__device__ const float TW32R[16] = {
    1.0f, 0.98078528040323045f, 0.92387953251128676f, 0.83146961230254524f,
    0.70710678118654752f, 0.55557023301960222f, 0.38268343236508977f, 0.19509032201612827f,
    0.0f, -0.19509032201612827f, -0.38268343236508977f, -0.55557023301960222f,
    -0.70710678118654752f, -0.83146961230254524f, -0.92387953251128676f, -0.98078528040323045f };
__device__ const float TW32I[16] = {
    0.0f, -0.19509032201612827f, -0.38268343236508977f, -0.55557023301960222f,
    -0.70710678118654752f, -0.83146961230254524f, -0.92387953251128676f, -0.98078528040323045f,
    -1.0f, -0.98078528040323045f, -0.92387953251128676f, -0.83146961230254524f,
    -0.70710678118654752f, -0.55557023301960222f, -0.38268343236508977f, -0.19509032201612827f };

__device__ const int BR4[16] = {0,8,4,12,2,10,6,14,1,9,5,13,3,11,7,15};

// DIF stage for register FFT of size 16, butterfly half-span H.
template<int H>
__device__ __forceinline__ void stage16(float2* y) {
    #pragma unroll
    for (int g = 0; g < 16; g += 2*H) {
        #pragma unroll
        for (int j = 0; j < H; j++) {
            float2 u = y[g+j], v = y[g+j+H];
            y[g+j] = cadd(u, v);
            float2 d = csub(u, v);
            const int m = j * (16 / H);
            y[g+j+H] = (j == 0) ? d : cmul(d, make_float2(TW32R[m], TW32I[m]));
        }
    }
}
__device__ __forceinline__ void fft16(float2* y) {
    stage16<8>(y); stage16<4>(y); stage16<2>(y); stage16<1>(y);
}   // y[p] = OUT[BR4[p]]

// wp[m] = w^m, m=0..15, mult depth <= 3 (VALU-computed, no load batching)
__device__ __forceinline__ void pow16(float2 w, float2* wp) {
    wp[0] = make_float2(1.f, 0.f);
    wp[1] = w;
    wp[2] = cmul(w, w);
    wp[3] = cmul(wp[2], w);
    wp[4] = cmul(wp[2], wp[2]);
    wp[5] = cmul(wp[4], wp[1]);
    wp[6] = cmul(wp[4], wp[2]);
    wp[7] = cmul(wp[4], wp[3]);
    wp[8] = cmul(wp[4], wp[4]);
    wp[9] = cmul(wp[8], wp[1]);
    wp[10] = cmul(wp[8], wp[2]);
    wp[11] = cmul(wp[8], wp[3]);
    wp[12] = cmul(wp[8], wp[4]);
    wp[13] = cmul(wp[8], wp[5]);
    wp[14] = cmul(wp[8], wp[6]);
    wp[15] = cmul(wp[8], wp[7]);
}

// ws layout (float2): [0,512) W_8192^u | [512,544) W_512^j | [544,1568) W_2048^t | [1568,1576) W_16384^i
static __global__ void init_tw(float2* __restrict__ ws) {
    int g = blockIdx.x * 1024 + threadIdx.x;
    if (g < 512) {
        ws[g] = make_float2((float)cos(DPI*g/4096.0), (float)(-sin(DPI*g/4096.0)));
    } else if (g < 544) {
        int j = g - 512;
        ws[g] = make_float2((float)cos(DPI*j/256.0), (float)(-sin(DPI*j/256.0)));
    } else if (g < 1568) {
        int q = g - 544;
        ws[g] = make_float2((float)cos(DPI*q/1024.0), (float)(-sin(DPI*q/1024.0)));
    } else if (g < 1576) {
        int i = g - 1568;
        ws[g] = make_float2((float)cos(DPI*i/8192.0), (float)(-sin(DPI*i/8192.0)));
    }
}

// raw barrier, LDS-visibility only: does NOT drain vmcnt (keeps the staging DMA in flight)
__device__ __forceinline__ void bar_lgkm() {
    __asm__ __volatile__("s_waitcnt lgkmcnt(0)" ::: "memory");
    __builtin_amdgcn_s_barrier();
}
// full barrier: guarantees DMA (vmcnt) completion before anyone proceeds
__device__ __forceinline__ void bar_full() {
    __asm__ __volatile__("s_waitcnt vmcnt(0) lgkmcnt(0)" ::: "memory");
    __builtin_amdgcn_s_barrier();
}

// One row-pair, straight-line (the proven r5 body). noinline => its own scheduling
// region and register allocation: the caller's loop cannot induce cross-row hoisting.
__device__ __attribute__((noinline)) void process_row(
    const float* __restrict__ tmpl, const float* __restrict__ strn,
    const float2* __restrict__ ws, float* __restrict__ out,
    int row, int staged, int pref)
{
    __shared__ float2 Z[16384];                 // 128 KiB, persists across calls
    float* F = reinterpret_cast<float*>(Z);
    int*   I = reinterpret_cast<int*>(Z);

    const int t    = threadIdx.x;               // 0..1023
    const int half = t >> 9;                    // 0 = strain, 1 = template
    const int u    = t & 511;
    const float ALPHA = 1.1920928955078125e-7f; // 4*DF/fs^2 = 2^-23

    row    = __builtin_amdgcn_readfirstlane(row);
    staged = __builtin_amdgcn_readfirstlane(staged);
    pref   = __builtin_amdgcn_readfirstlane(pref);

    const float2* tw8192 = ws;                  // W_8192^u, u<512
    const float2* tw512  = ws + 512;            // W_512^j,  j<32
    const float2* twC    = ws + 544;            // W_2048^t, t<1024
    const float2* twI    = ws + 1568;           // W_16384^i, i<8

    float2* Zh = Z + (half << 13);
    const float2 cv = twC[t];

    const int k1s = u >> 5, js = u & 31;        // stage-2 coords
    const int f = u >> 8, k1t = (u >> 4) & 15, k2t = u & 15;   // stage-3 coords

    float2 y[16];

    // -------- load row (template from LDS staging when staged) + stage 1 --------
    if (half == 0) {
        const float2* x = reinterpret_cast<const float2*>(strn + (size_t)row * 16384);
        #pragma unroll
        for (int n1 = 0; n1 < 16; n1++) y[n1] = x[n1*512 + u];
    } else if (staged) {
        #pragma unroll
        for (int n1 = 0; n1 < 16; n1++) y[n1] = Z[8192 + n1*512 + u];   // staged raw row
    } else {
        const float2* x = reinterpret_cast<const float2*>(tmpl + (size_t)row * 16384);
        #pragma unroll
        for (int n1 = 0; n1 < 16; n1++) y[n1] = x[n1*512 + u];
    }
    fft16(y);
    __syncthreads();                            // staging reads done before L1 overwrites
    {
        float2 wp[16]; pow16(tw8192[u], wp);
        #pragma unroll
        for (int p = 0; p < 16; p++) {
            int k1 = BR4[p];
            float2 val = y[p];
            if (k1 > 0) val = cmul(val, wp[k1]);
            Zh[(u << 4) | (k1 ^ (u & 15))] = val;   // L1[u][k1], swizzled
        }
    }
    __syncthreads();

    // -------- stage 2: fft16 over n2, twiddle W_512^{j*k2} --------
    #pragma unroll
    for (int n2 = 0; n2 < 16; n2++)
        y[n2] = Zh[((n2*32 + js) << 4) | (k1s ^ (js & 15))];
    __syncthreads();                            // all L1 reads done before L2 writes
    fft16(y);
    {
        float2 wq[16]; pow16(tw512[js], wq);
        #pragma unroll
        for (int p = 0; p < 16; p++) {
            int k2 = BR4[p];
            float2 val = y[p];
            if (k2 > 0) val = cmul(val, wq[k2]);
            Zh[(k1s << 9) + (k2 << 5) + (js ^ k2)] = val;  // L2[k1][k2][j], swizzled
        }
    }
    __syncthreads();

    // -------- stage 3: radix-2 fused into the load + fft16 over j2 --------
    const int base = (k1t << 9) + (k2t << 5);
    if (f == 0) {
        #pragma unroll
        for (int j2 = 0; j2 < 16; j2++) {
            float2 a = Zh[base + (j2 ^ k2t)];
            float2 b = Zh[base + (j2 ^ k2t) + 16];
            y[j2] = cadd(a, b);
        }
    } else {
        #pragma unroll
        for (int j2 = 0; j2 < 16; j2++) {
            float2 a = Zh[base + (j2 ^ k2t)];
            float2 b = Zh[base + (j2 ^ k2t) + 16];
            y[j2] = cmul(csub(a, b), make_float2(TW32R[j2], TW32I[j2]));
        }
    }
    __syncthreads();                            // all L2 reads done before spectrum store
    fft16(y);
    #pragma unroll
    for (int p = 0; p < 16; p++) {
        int s2 = BR4[p];
        int k = k1t + (k2t << 4) + (f << 8) + (s2 << 9);
        Zh[(k & ~31) | ((k & 31) ^ ((k >> 5) & 31))] = y[p];  // natural k, swizzled low5
    }
    __syncthreads();                            // both spectra ready

    // -------- rfft unpack + pointwise products, 8 bins/thread --------
    float2* ZS = Z;
    float2* ZH = Z + 8192;
    float2 zs0 = ZS[0], zh0 = ZH[0];
    const float s_nyq = zs0.x - zs0.y;
    const float h_nyq = zh0.x - zh0.y;

    float hh[8], hs[8];                          // |H|^2, Re(conj(H)*S)
    #pragma unroll
    for (int i = 0; i < 8; i++) {
        int k = (t << 3) + i;
        int m = (8192 - k) & 8191;
        int ak = (k & ~31) | ((k & 31) ^ ((k >> 5) & 31));
        int am = (m & ~31) | ((m & 31) ^ ((m >> 5) & 31));
        float2 As = ZS[ak], Bs = ZS[am];
        float2 Ah = ZH[ak], Bh = ZH[am];
        float2 w = cmul(cv, twI[i]);             // W_16384^k
        float Er = 0.5f*(As.x + Bs.x), Ei = 0.5f*(As.y - Bs.y);
        float Dr = 0.5f*(As.x - Bs.x), Di = 0.5f*(As.y + Bs.y);
        float sr = Er + w.x*Di + w.y*Dr;
        float si = Ei + w.y*Di - w.x*Dr;
        Er = 0.5f*(Ah.x + Bh.x); Ei = 0.5f*(Ah.y - Bh.y);
        Dr = 0.5f*(Ah.x - Bh.x); Di = 0.5f*(Ah.y + Bh.y);
        float hr = Er + w.x*Di + w.y*Dr;
        float hi = Ei + w.y*Di - w.x*Dr;
        hh[i] = hr*hr + hi*hi;
        hs[i] = hr*sr + hi*si;
    }
    __syncthreads();                             // all spectrum reads done; upper half dead

    // -------- prefetch next row's template into upper half via LDS-DMA (no VGPRs) --------
    if (pref) {
        typedef const __attribute__((address_space(1))) char gchar;
        typedef __attribute__((address_space(3))) char lchar;
        gchar* src = (gchar*)(tmpl + (size_t)(row + 1) * 16384);
        lchar* dst = (lchar*)(char*)(Z + 8192);
        const int wave = t >> 6, lane = t & 63;
        #pragma unroll
        for (int c = 0; c < 4; c++) {
            const int off = ((wave * 4 + c) << 10);          // 1 KiB per wave-chunk
            __builtin_amdgcn_global_load_lds(
                (const __attribute__((address_space(1))) void*)(src + off + (lane << 4)),
                (__attribute__((address_space(3))) void*)(dst + off),
                16, 0, 0);
        }
    }

    // -------- reductions (LDS-only; raw lgkm barriers keep the DMA in flight) --------
    const int SCANW = 8456;                      // lower half, beyond cum (<=F[8448])
    const int EDG   = 8473;                      // 17 ints
    const int BINS  = 8496;                      // 16 floats
    const int TOT   = 8513;

    float run = 0.f;
    #pragma unroll
    for (int i = 0; i < 8; i++) run += ALPHA * hh[i];

    const int lane = t & 63, wid = t >> 6;
    float v = run;
    #pragma unroll
    for (int off = 1; off < 64; off <<= 1) {
        float o = __shfl_up(v, off, 64);
        if (lane >= off) v += o;
    }
    if (lane == 63) F[SCANW + wid] = v;
    bar_lgkm();
    float wbase = 0.f;
    #pragma unroll
    for (int w2 = 0; w2 < 15; w2++) if (w2 < wid) wbase += F[SCANW + w2];
    float base2 = wbase + v - run;               // exclusive prefix

    float cum = base2;
    #pragma unroll
    for (int i = 0; i < 8; i++) {                // cum at phys(k)=k+(k>>5)
        cum += ALPHA * hh[i];
        int k = (t << 3) + i;
        F[k + (k >> 5)] = cum;
    }
    if (t == 1023) F[8448] = cum + ALPHA * h_nyq * h_nyq;   // cum_h[8192]
    bar_lgkm();

    float total_h = F[8448];
    if (t < 17) {
        float target = (float)t * 0.0625f * total_h;
        int lo = 0, hi = 8193;
        while (lo < hi) {
            int mid = (lo + hi) >> 1;
            float vv = F[mid + (mid >> 5)];
            if (vv <= target) lo = mid + 1; else hi = mid;
        }
        I[EDG + t] = lo < 8192 ? lo : 8192;
    }
    if (t >= 64 && t < 80) F[BINS + (t - 64)] = 0.f;
    if (t == 80) F[TOT] = 0.f;
    bar_lgkm();

    int e[17];
    #pragma unroll
    for (int i = 0; i < 17; i++) e[i] = I[EDG + i];

    float invs = 1.0f / sqrtf(total_h);
    float qs   = ALPHA * invs;

    float tot = 0.f, acc = 0.f;
    int   cur = -1;
    #pragma unroll
    for (int i = 0; i < 8; i++) {
        int   k = (t << 3) + i;
        float r = qs * hs[i];
        tot += r;
        int bn = -1;                             // k in bin bn iff e[bn] < k <= e[bn+1]
        #pragma unroll
        for (int j = 0; j < 17; j++) bn += (e[j] < k) ? 1 : 0;
        if (bn != cur) {
            if (cur >= 0) atomicAdd(&F[BINS + cur], acc);
            acc = 0.f;
            cur = bn;
        }
        acc += r;
    }
    if (cur >= 0) atomicAdd(&F[BINS + cur], acc);

    #pragma unroll
    for (int off = 32; off > 0; off >>= 1) tot += __shfl_down(tot, off);
    if ((t & 63) == 0) atomicAdd(&F[TOT], tot);

    if (t == 0) {                                // Nyquist term (k = 8192)
        float rn = qs * (h_nyq * s_nyq);
        atomicAdd(&F[TOT], rn);
        int bn = -1;
        #pragma unroll
        for (int j = 0; j < 17; j++) bn += (e[j] < 8192) ? 1 : 0;
        if (bn >= 0) atomicAdd(&F[BINS + bn], rn);
    }
    bar_lgkm();

    if (t == 0) {
        float total = F[TOT];
        float mean  = total * 0.0625f;
        float chisq = 0.f;
        #pragma unroll
        for (int j = 0; j < 16; j++) {
            float d = F[BINS + j] - mean;
            chisq += d * d;
        }
        out[row] = chisq * (16.0f / 15.0f);
    }

    bar_full();   // DMA complete + all LDS settled before the next call touches Z
}

__launch_bounds__(1024, 4)
static __global__ void chisq_kernel(const float* __restrict__ tmpl,
                                    const float* __restrict__ strn,
                                    const float2* __restrict__ ws,
                                    float* __restrict__ out,
                                    int rows)
{
    const int r0 = blockIdx.x * RPB;
    #pragma clang loop unroll(disable)
    for (int rr = 0; rr < RPB; rr++) {
        const int row = r0 + rr;
        if (row >= rows) break;                  // block-uniform
        process_row(tmpl, strn, ws, out, row,
                    rr > 0 ? 1 : 0,
                    (rr + 1 < RPB && row + 1 < rows) ? 1 : 0);
    }
}

extern "C" void kernel_launch(void* const* d_in, const int* in_sizes, int n_in,
                              void* d_out, int out_size, void* d_ws, size_t ws_size,
                              hipStream_t stream) {
    const float* tmpl = (const float*)d_in[0];
    const float* strn = (const float*)d_in[1];
    float* outp = (float*)d_out;
    float2* ws  = (float2*)d_ws;                 // ~12.3 KiB twiddle tables

    int rows = in_sizes[0] / 16384;              // 1024
    int nblk = (rows + RPB - 1) / RPB;           // 256 persistent blocks (1 per CU)

    hipLaunchKernelGGL(init_tw, dim3(2), dim3(1024), 0, stream, ws);
    hipLaunchKernelGGL(chisq_kernel, dim3(nblk), dim3(1024), 0, stream,
                       tmpl, strn, ws, outp, rows);
}

// Round 11
// 91.237 us; speedup vs baseline: 2.3416x; 1.2567x over previous
//
#include <hip/hip_runtime.h>
#include <math.h>

#define DPI 3.14159265358979323846

__device__ __forceinline__ float2 cmul(float2 a, float2 b) {
    return make_float2(a.x*b.x - a.y*b.y, a.x*b.y + a.y*b.x);
}
__device__ __forceinline__ float2 cadd(float2 a, float2 b){ return make_float2(a.x+b.x, a.y+b.y); }
__device__ __forceinline__ float2 csub(float2 a, float2 b){ return make_float2(a.x-b.x, a.y-b.y); }

// W_32^m = (cos, -sin)(2*pi*m/32), m = 0..15
__device__ const float TW32R[16] = {
    1.0f, 0.98078528040323045f, 0.92387953251128676f, 0.83146961230254524f,
    0.70710678118654752f, 0.55557023301960222f, 0.38268343236508977f, 0.19509032201612827f,
    0.0f, -0.19509032201612827f, -0.38268343236508977f, -0.55557023301960222f,
    -0.70710678118654752f, -0.83146961230254524f, -0.92387953251128676f, -0.98078528040323045f };
__device__ const float TW32I[16] = {
    0.0f, -0.19509032201612827f, -0.38268343236508977f, -0.55557023301960222f,
    -0.70710678118654752f, -0.83146961230254524f, -0.92387953251128676f, -0.98078528040323045f,
    -1.0f, -0.98078528040323045f, -0.92387953251128676f, -0.83146961230254524f,
    -0.70710678118654752f, -0.55557023301960222f, -0.38268343236508977f, -0.19509032201612827f };

__device__ const int BR4[16] = {0,8,4,12,2,10,6,14,1,9,5,13,3,11,7,15};

// DIF stage for register FFT of size 16, butterfly half-span H.
template<int H>
__device__ __forceinline__ void stage16(float2* y) {
    #pragma unroll
    for (int g = 0; g < 16; g += 2*H) {
        #pragma unroll
        for (int j = 0; j < H; j++) {
            float2 u = y[g+j], v = y[g+j+H];
            y[g+j] = cadd(u, v);
            float2 d = csub(u, v);
            const int m = j * (16 / H);
            y[g+j+H] = (j == 0) ? d : cmul(d, make_float2(TW32R[m], TW32I[m]));
        }
    }
}
__device__ __forceinline__ void fft16(float2* y) {
    stage16<8>(y); stage16<4>(y); stage16<2>(y); stage16<1>(y);
}   // y[p] = OUT[BR4[p]]

// wp[m] = w^m, m=0..15, mult depth <= 3 (VALU-computed, no load batching)
__device__ __forceinline__ void pow16(float2 w, float2* wp) {
    wp[0] = make_float2(1.f, 0.f);
    wp[1] = w;
    wp[2] = cmul(w, w);
    wp[3] = cmul(wp[2], w);
    wp[4] = cmul(wp[2], wp[2]);
    wp[5] = cmul(wp[4], wp[1]);
    wp[6] = cmul(wp[4], wp[2]);
    wp[7] = cmul(wp[4], wp[3]);
    wp[8] = cmul(wp[4], wp[4]);
    wp[9] = cmul(wp[8], wp[1]);
    wp[10] = cmul(wp[8], wp[2]);
    wp[11] = cmul(wp[8], wp[3]);
    wp[12] = cmul(wp[8], wp[4]);
    wp[13] = cmul(wp[8], wp[5]);
    wp[14] = cmul(wp[8], wp[6]);
    wp[15] = cmul(wp[8], wp[7]);
}

// ws layout (float2):
// [0,512)      W_8192^u   (stage-1 pow16 base)
// [512,544)    W_512^j    (stage-2 pow16 base)
// [544,1056)   W_1024^t   (unpack base, k=16t+i)
// [1056,1072)  W_16384^i  (i<16)
static __global__ void init_tw(float2* __restrict__ ws) {
    int g = blockIdx.x * 1024 + threadIdx.x;
    if (g < 512) {
        ws[g] = make_float2((float)cos(DPI*g/4096.0), (float)(-sin(DPI*g/4096.0)));
    } else if (g < 544) {
        int j = g - 512;
        ws[g] = make_float2((float)cos(DPI*j/256.0), (float)(-sin(DPI*j/256.0)));
    } else if (g < 1056) {
        int q = g - 544;
        ws[g] = make_float2((float)cos(DPI*q/512.0), (float)(-sin(DPI*q/512.0)));
    } else if (g < 1072) {
        int i = g - 1056;
        ws[g] = make_float2((float)cos(DPI*i/8192.0), (float)(-sin(DPI*i/8192.0)));
    }
}

__launch_bounds__(512, 2)   // 512-thread blocks compile at 128 VGPRs (r3-verified)
static __global__ void chisq_kernel(const float* __restrict__ tmpl,
                                    const float* __restrict__ strn,
                                    const float2* __restrict__ ws,
                                    float* __restrict__ out)
{
    __shared__ float2 Z[8192];                  // 64 KiB, one spectrum at a time
    float* F = reinterpret_cast<float*>(Z);
    int*   I = reinterpret_cast<int*>(Z);

    const int t   = threadIdx.x;                // 0..511
    const int row = blockIdx.x;
    const float ALPHA = 1.1920928955078125e-7f; // 4*DF/fs^2 = 2^-23

    const float2* tw8192 = ws;                  // W_8192^u
    const float2* tw512  = ws + 512;            // W_512^j
    const float2* twB    = ws + 544;            // W_1024^t
    const float2* twI    = ws + 1056;           // W_16384^i, i<16

    const int k1s = t >> 5, js = t & 31;        // stage-2 coords
    const int f = t >> 8, k1t = (t >> 4) & 15, k2t = t & 15;   // stage-3 coords

    // -------- 8192-point FFT of one packed real row into Z (swizzled natural order) --------
    // Caller must __syncthreads() before invoking (Z consumers done). 5 internal barriers.
    auto run_fft = [&](const float* srcrow) {
        float2 y[16];
        const float2* x = reinterpret_cast<const float2*>(srcrow);
        #pragma unroll
        for (int n1 = 0; n1 < 16; n1++) y[n1] = x[n1*512 + t];
        fft16(y);
        {
            float2 wp[16]; pow16(tw8192[t], wp);
            #pragma unroll
            for (int p = 0; p < 16; p++) {
                int k1 = BR4[p];
                float2 val = y[p];
                if (k1 > 0) val = cmul(val, wp[k1]);
                Z[(t << 4) | (k1 ^ (t & 15))] = val;   // L1[u][k1], swizzled
            }
        }
        __syncthreads();
        #pragma unroll
        for (int n2 = 0; n2 < 16; n2++)
            y[n2] = Z[((n2*32 + js) << 4) | (k1s ^ (js & 15))];
        __syncthreads();                         // all L1 reads done before L2 writes
        fft16(y);
        {
            float2 wq[16]; pow16(tw512[js], wq);
            #pragma unroll
            for (int p = 0; p < 16; p++) {
                int k2 = BR4[p];
                float2 val = y[p];
                if (k2 > 0) val = cmul(val, wq[k2]);
                Z[(k1s << 9) + (k2 << 5) + (js ^ k2)] = val;  // L2[k1][k2][j], swizzled
            }
        }
        __syncthreads();
        const int base = (k1t << 9) + (k2t << 5);
        if (f == 0) {
            #pragma unroll
            for (int j2 = 0; j2 < 16; j2++) {
                float2 a = Z[base + (j2 ^ k2t)];
                float2 b = Z[base + (j2 ^ k2t) + 16];
                y[j2] = cadd(a, b);
            }
        } else {
            #pragma unroll
            for (int j2 = 0; j2 < 16; j2++) {
                float2 a = Z[base + (j2 ^ k2t)];
                float2 b = Z[base + (j2 ^ k2t) + 16];
                y[j2] = cmul(csub(a, b), make_float2(TW32R[j2], TW32I[j2]));
            }
        }
        __syncthreads();                         // all L2 reads done before spectrum store
        fft16(y);
        #pragma unroll
        for (int p = 0; p < 16; p++) {
            int s2 = BR4[p];
            int k = k1t + (k2t << 4) + (f << 8) + (s2 << 9);
            Z[(k & ~31) | ((k & 31) ^ ((k >> 5) & 31))] = y[p];  // natural k, swizzled low5
        }
        __syncthreads();                         // spectrum ready
    };

    // -------- phase A: strain FFT + unpack S spectrum to registers (16 bins/thread) --------
    float sre[16], sim[16];
    float s_nyq;
    run_fft(strn + (size_t)row * 16384);
    {
        const float2 cv = twB[t];
        #pragma unroll
        for (int i = 0; i < 16; i++) {
            int k = (t << 4) + i;
            int m = (8192 - k) & 8191;
            int ak = (k & ~31) | ((k & 31) ^ ((k >> 5) & 31));
            int am = (m & ~31) | ((m & 31) ^ ((m >> 5) & 31));
            float2 A = Z[ak], B = Z[am];
            float2 w = cmul(cv, twI[i]);         // W_16384^k
            float Er = 0.5f*(A.x + B.x), Ei = 0.5f*(A.y - B.y);
            float Dr = 0.5f*(A.x - B.x), Di = 0.5f*(A.y + B.y);
            sre[i] = Er + w.x*Di + w.y*Dr;
            sim[i] = Ei + w.y*Di - w.x*Dr;
        }
        float2 z0 = Z[0];
        s_nyq = z0.x - z0.y;
    }
    __syncthreads();                             // unpack reads done; Z free

    // -------- phase B: template FFT + unpack H, combine into hh/hs --------
    float hh[16], hs[16];                        // |H|^2, Re(conj(H)*S)
    float h_nyq;
    run_fft(tmpl + (size_t)row * 16384);
    {
        const float2 cv = twB[t];
        #pragma unroll
        for (int i = 0; i < 16; i++) {
            int k = (t << 4) + i;
            int m = (8192 - k) & 8191;
            int ak = (k & ~31) | ((k & 31) ^ ((k >> 5) & 31));
            int am = (m & ~31) | ((m & 31) ^ ((m >> 5) & 31));
            float2 A = Z[ak], B = Z[am];
            float2 w = cmul(cv, twI[i]);
            float Er = 0.5f*(A.x + B.x), Ei = 0.5f*(A.y - B.y);
            float Dr = 0.5f*(A.x - B.x), Di = 0.5f*(A.y + B.y);
            float hr = Er + w.x*Di + w.y*Dr;
            float hi = Ei + w.y*Di - w.x*Dr;
            hh[i] = hr*hr + hi*hi;
            hs[i] = hr*sre[i] + hi*sim[i];
        }
        float2 z0 = Z[0];
        h_nyq = z0.x - z0.y;
    }
    __syncthreads();                             // unpack reads done; Z free for cum

    // -------- cum_h: wave shuffle scan over 8 waves --------
    const int SCANW = 8456;                      // beyond cum (<= F[8448])
    const int EDG   = 8466;                      // 17 ints
    const int BINS  = 8484;                      // 16 floats
    const int TOT   = 8501;

    float run = 0.f;
    #pragma unroll
    for (int i = 0; i < 16; i++) run += ALPHA * hh[i];

    const int lane = t & 63, wid = t >> 6;
    float v = run;
    #pragma unroll
    for (int off = 1; off < 64; off <<= 1) {
        float o = __shfl_up(v, off, 64);
        if (lane >= off) v += o;
    }
    if (lane == 63) F[SCANW + wid] = v;
    __syncthreads();
    float wbase = 0.f;
    #pragma unroll
    for (int w2 = 0; w2 < 7; w2++) if (w2 < wid) wbase += F[SCANW + w2];
    float base2 = wbase + v - run;               // exclusive prefix

    float cum = base2;
    #pragma unroll
    for (int i = 0; i < 16; i++) {               // cum at phys(k)=k+(k>>5)
        cum += ALPHA * hh[i];
        int k = (t << 4) + i;
        F[k + (k >> 5)] = cum;
    }
    if (t == 511) F[8448] = cum + ALPHA * h_nyq * h_nyq;   // cum_h[8192]
    __syncthreads();

    // -------- edges (searchsorted right) + bin init --------
    float total_h = F[8448];
    if (t < 17) {
        float target = (float)t * 0.0625f * total_h;
        int lo = 0, hi = 8193;
        while (lo < hi) {
            int mid = (lo + hi) >> 1;
            float vv = F[mid + (mid >> 5)];
            if (vv <= target) lo = mid + 1; else hi = mid;
        }
        I[EDG + t] = lo < 8192 ? lo : 8192;
    }
    if (t >= 64 && t < 80) F[BINS + (t - 64)] = 0.f;
    if (t == 80) F[TOT] = 0.f;
    __syncthreads();

    int e[17];
    #pragma unroll
    for (int i = 0; i < 17; i++) e[i] = I[EDG + i];

    float invs = 1.0f / sqrtf(total_h);
    float qs   = ALPHA * invs;

    // -------- segmented bin sums + total --------
    float tot = 0.f, acc = 0.f;
    int   cur = -1;
    #pragma unroll
    for (int i = 0; i < 16; i++) {
        int   k = (t << 4) + i;
        float r = qs * hs[i];
        tot += r;
        int bn = -1;                             // k in bin bn iff e[bn] < k <= e[bn+1]
        #pragma unroll
        for (int j = 0; j < 17; j++) bn += (e[j] < k) ? 1 : 0;
        if (bn != cur) {
            if (cur >= 0) atomicAdd(&F[BINS + cur], acc);
            acc = 0.f;
            cur = bn;
        }
        acc += r;
    }
    if (cur >= 0) atomicAdd(&F[BINS + cur], acc);

    #pragma unroll
    for (int off = 32; off > 0; off >>= 1) tot += __shfl_down(tot, off);
    if ((t & 63) == 0) atomicAdd(&F[TOT], tot);

    if (t == 0) {                                // Nyquist term (k = 8192)
        float rn = qs * (h_nyq * s_nyq);
        atomicAdd(&F[TOT], rn);
        int bn = -1;
        #pragma unroll
        for (int j = 0; j < 17; j++) bn += (e[j] < 8192) ? 1 : 0;
        if (bn >= 0) atomicAdd(&F[BINS + bn], rn);
    }
    __syncthreads();

    if (t == 0) {
        float total = F[TOT];
        float mean  = total * 0.0625f;
        float chisq = 0.f;
        #pragma unroll
        for (int j = 0; j < 16; j++) {
            float d = F[BINS + j] - mean;
            chisq += d * d;
        }
        out[row] = chisq * (16.0f / 15.0f);
    }
}

extern "C" void kernel_launch(void* const* d_in, const int* in_sizes, int n_in,
                              void* d_out, int out_size, void* d_ws, size_t ws_size,
                              hipStream_t stream) {
    const float* tmpl = (const float*)d_in[0];
    const float* strn = (const float*)d_in[1];
    float* outp = (float*)d_out;
    float2* ws  = (float2*)d_ws;                 // ~8.4 KiB twiddle tables

    int rows = in_sizes[0] / 16384;              // 1024

    hipLaunchKernelGGL(init_tw, dim3(2), dim3(1024), 0, stream, ws);
    hipLaunchKernelGGL(chisq_kernel, dim3(rows), dim3(512), 0, stream,
                       tmpl, strn, ws, outp);
}